// Round 12
// baseline (237.796 us; speedup 1.0000x reference)
//
#include <hip/hip_runtime.h>
#include <hip/hip_fp16.h>
#include <type_traits>

#define N_NODES 100000
#define N_EDGES 1200000
#define N_FEAT 128
#define HIDDEN 64
#define N_CLASSES 40

// bucket sort parameters
#define BSHIFT 9
#define BMASK 511
#define BUCKET_NODES 512
#define NBK ((N_NODES + BUCKET_NODES - 1) / BUCKET_NODES)  // 196
#define BCAP 8192
#define CHUNK 2048

typedef _Float16 f16x8 __attribute__((ext_vector_type(8)));
typedef float f32x4 __attribute__((ext_vector_type(4)));

// ---- bucket pass: edges -> bucket-major packed array ----
// gcursor zero-initialized (memset); relative cursors, so gcursor[b] ends as
// bucket b's total. Direct 4B scatter into per-block reserved ranges: runs are
// ~40B per bucket per block and L2 absorbs them (lines fill before eviction),
// so no LDS staging/coalescing pass is needed.

__global__ __launch_bounds__(256) void bucket_kernel(const int* __restrict__ row,
                                                     const int* __restrict__ col,
                                                     int* __restrict__ gcursor,
                                                     unsigned* __restrict__ bke, int E) {
    __shared__ int hist[NBK];
    __shared__ int gbase[NBK];
    __shared__ int lcnt[NBK];

    const int t = threadIdx.x;
    const int e0 = blockIdx.x * CHUNK;
    const int nE = min(CHUNK, E - e0);

    for (int i = t; i < NBK; i += 256) {
        hist[i] = 0;
        lcnt[i] = 0;
    }
    __syncthreads();

    for (int i = t; i < nE; i += 256) atomicAdd(&hist[col[e0 + i] >> BSHIFT], 1);
    __syncthreads();

    if (t < NBK) {
        int v = hist[t];
        gbase[t] = t * BCAP + ((v > 0) ? atomicAdd(&gcursor[t], v) : 0);
    }
    __syncthreads();

    for (int i = t; i < nE; i += 256) {
        int r = row[e0 + i];
        int c = col[e0 + i];
        int b = c >> BSHIFT;
        int pos = atomicAdd(&lcnt[b], 1);
        bke[(size_t)gbase[b] + pos] = ((unsigned)r << BSHIFT) | (unsigned)(c & BMASK);
    }
}

// ---- fused per-bucket: bucketBase scan + hist -> rowptr + dinv -> scatter CSR ----

__global__ __launch_bounds__(256) void place_kernel(const int* __restrict__ gcursor,
                                                    const unsigned* __restrict__ bke,
                                                    int* __restrict__ rowptr,
                                                    float* __restrict__ dinv,
                                                    int* __restrict__ csr_src, int n) {
    __shared__ int hist[BUCKET_NODES];
    __shared__ int cur[BUCKET_NODES];
    __shared__ int tsum[256];

    const int b = blockIdx.x, t = threadIdx.x;
    const int node0 = b << BSHIFT;
    const int nNodes = min(BUCKET_NODES, n - node0);

    // bucket base: exclusive prefix over the 196 bucket counts (gcursor holds counts)
    const int myCnt = (t < NBK) ? gcursor[t] : 0;
    tsum[t] = myCnt;
    __syncthreads();
    for (int d = 1; d < 256; d <<= 1) {
        int add = (t >= d) ? tsum[t - d] : 0;
        __syncthreads();
        tsum[t] += add;
        __syncthreads();
    }
    const int base = tsum[b] - gcursor[b];  // exclusive prefix at b
    const int nb = gcursor[b];
    __syncthreads();

    hist[t] = 0;
    hist[t + 256] = 0;
    __syncthreads();

    const unsigned* src = bke + (size_t)b * BCAP;
    for (int i = t; i < nb; i += 256) atomicAdd(&hist[src[i] & BMASK], 1);
    __syncthreads();

    // 512-wide exclusive scan: thread t owns elements 2t, 2t+1
    const int c0 = hist[2 * t];
    const int c1 = hist[2 * t + 1];
    const int s = c0 + c1;
    tsum[t] = s;
    __syncthreads();
    for (int d = 1; d < 256; d <<= 1) {
        int add = (t >= d) ? tsum[t - d] : 0;
        __syncthreads();
        tsum[t] += add;
        __syncthreads();
    }
    const int e0 = base + tsum[t] - s;
    const int e1 = e0 + c0;

    cur[2 * t] = e0;
    cur[2 * t + 1] = e1;
    if (2 * t < nNodes) {
        rowptr[node0 + 2 * t] = e0;
        dinv[node0 + 2 * t] = rsqrtf((float)(c0 + 1));
    }
    if (2 * t + 1 < nNodes) {
        rowptr[node0 + 2 * t + 1] = e1;
        dinv[node0 + 2 * t + 1] = rsqrtf((float)(c1 + 1));
    }
    if (t == 0 && node0 + nNodes == n) rowptr[n] = N_EDGES;
    __syncthreads();

    for (int i = t; i < nb; i += 256) {
        unsigned p = src[i];
        int pos = atomicAdd(&cur[p & BMASK], 1);
        csr_src[pos] = (int)(p >> BSHIFT);
    }
}

// ---------------- MFMA GEMM with scaled-fp16 epilogue ----------------
// Hs[node, f<NOUT] = fp16( (X @ W)[node,f] * dinv[node] ), row stride OSTRIDE halves.
// XT = float (layer 1, cvt in-flight) or _Float16 (layer 2, native A-frags).
// v_mfma_f32_16x16x32_f16 layouts (m89/m120 verified):
//   A[m=lane&15][k=quad*8+j], B[k=quad*8+j][n=lane&15], C: col=lane&15,row=quad*4+reg.

template <typename XT, int K, int XSTRIDE, int NOUT, int NOUT_PAD, int OSTRIDE>
__global__ __launch_bounds__(256) void gemm_mfma_kernel(const XT* __restrict__ X,
                                                        const float* __restrict__ W,
                                                        const float* __restrict__ dinv,
                                                        __half* __restrict__ Hs, int M) {
    constexpr int KCH = K / 32;
    constexpr int NT = NOUT_PAD / 16;
    constexpr int WPITCH = NOUT_PAD + 2;

    __shared__ _Float16 wh[K * WPITCH];
    __shared__ float sdinv[256];

    const int tid = threadIdx.x;
    const int bnode0 = blockIdx.x * 256;

    for (int i = tid; i < K * NOUT_PAD; i += 256) {
        int k = i / NOUT_PAD, n = i % NOUT_PAD;
        wh[k * WPITCH + n] = (n < NOUT) ? (_Float16)W[k * NOUT + n] : (_Float16)0.0f;
    }
    {
        int node = bnode0 + tid;
        sdinv[tid] = (node < M) ? dinv[node] : 0.f;
    }
    __syncthreads();

    const int wid = tid >> 6;
    const int lane = tid & 63;
    const int m = lane & 15;
    const int quad = lane >> 4;

    f16x8 bf[KCH][NT];
#pragma unroll
    for (int kc = 0; kc < KCH; ++kc)
#pragma unroll
        for (int nt = 0; nt < NT; ++nt)
#pragma unroll
            for (int j = 0; j < 8; ++j)
                bf[kc][nt][j] = wh[(kc * 32 + quad * 8 + j) * WPITCH + nt * 16 + m];

    for (int nt4 = 0; nt4 < 4; ++nt4) {
        const int nb = bnode0 + wid * 64 + nt4 * 16;
        if (nb >= M) break;
        const int rowi = min(nb + m, M - 1);
        const XT* xr = X + (size_t)rowi * XSTRIDE;

        f32x4 acc[NT];
#pragma unroll
        for (int nt = 0; nt < NT; ++nt) acc[nt] = (f32x4){0.f, 0.f, 0.f, 0.f};

#pragma unroll
        for (int kc = 0; kc < KCH; ++kc) {
            f16x8 af;
            if constexpr (std::is_same<XT, float>::value) {
                float4 u0 = *(const float4*)&xr[kc * 32 + quad * 8];
                float4 u1 = *(const float4*)&xr[kc * 32 + quad * 8 + 4];
                af[0] = (_Float16)u0.x;
                af[1] = (_Float16)u0.y;
                af[2] = (_Float16)u0.z;
                af[3] = (_Float16)u0.w;
                af[4] = (_Float16)u1.x;
                af[5] = (_Float16)u1.y;
                af[6] = (_Float16)u1.z;
                af[7] = (_Float16)u1.w;
            } else {
                af = *(const f16x8*)&xr[kc * 32 + quad * 8];
            }
#pragma unroll
            for (int nt = 0; nt < NT; ++nt)
                acc[nt] = __builtin_amdgcn_mfma_f32_16x16x32_f16(af, bf[kc][nt], acc[nt], 0, 0, 0);
        }

#pragma unroll
        for (int reg = 0; reg < 4; ++reg) {
            const int node = nb + quad * 4 + reg;
            if (node < M) {
                const float s = sdinv[node - bnode0];
#pragma unroll
                for (int nt = 0; nt < NT; ++nt) {
                    const int f = nt * 16 + m;
                    if (NOUT == NOUT_PAD || f < NOUT)
                        Hs[(size_t)node * OSTRIDE + f] = __float2half(acc[nt][reg] * s);
                }
            }
        }
    }
}

// ---------------- per-node wave gather, 8 row-slots x 8 chunk-lanes ----------------
// Edge pair pre-summed in fp16 (__hadd2, 4 packed adds) then fp32-accumulated:
// 20 VALU/iter vs 32. Extra fp16 rounding <= ~8 events/node, shrunk by dc scale.

__device__ inline void acc_row8(float (&acc)[8], uint4 u) {
    const __half2* hp = (const __half2*)&u;
#pragma unroll
    for (int k = 0; k < 4; ++k) {
        float2 f = __half22float2(hp[k]);
        acc[2 * k] += f.x;
        acc[2 * k + 1] += f.y;
    }
}

__device__ inline void acc_pair8(float (&acc)[8], uint4 u0, uint4 u1) {
    const __half2* a = (const __half2*)&u0;
    const __half2* b = (const __half2*)&u1;
#pragma unroll
    for (int k = 0; k < 4; ++k) {
        __half2 s = __hadd2(a[k], b[k]);
        float2 f = __half22float2(s);
        acc[2 * k] += f.x;
        acc[2 * k + 1] += f.y;
    }
}

template <typename OutT, int FCHUNKS, int HSTRIDE, int OUTSTRIDE, bool RELU>
__global__ __launch_bounds__(256) void gather8_kernel(const int* __restrict__ rowptr,
                                                      const int* __restrict__ csr_src,
                                                      const float* __restrict__ dinv,
                                                      const __half* __restrict__ hs,
                                                      const float* __restrict__ b,
                                                      OutT* __restrict__ out, int n) {
    const int wave = (blockIdx.x * blockDim.x + threadIdx.x) >> 6;
    const int lane = threadIdx.x & 63;
    if (wave >= n) return;
    const int c = wave;
    const int g = lane >> 3;  // row slot
    const int q = lane & 7;   // 16B chunk within row
    const bool qv = q < FCHUNKS;

    const float dc = dinv[c];
    const int eBeg = rowptr[c];
    const int eEnd = rowptr[c + 1];

    float acc[8];
#pragma unroll
    for (int j = 0; j < 8; ++j) acc[j] = 0.f;

    if (g == 0 && qv) {
        uint4 u = *(const uint4*)&hs[(size_t)c * HSTRIDE + q * 8];
        acc_row8(acc, u);
    }

    for (int e = eBeg; e < eEnd; e += 16) {
        const int i0 = e + g;
        const int i1 = e + 8 + g;
        int r0 = (i0 < eEnd) ? csr_src[i0] : -1;
        int r1 = (i1 < eEnd) ? csr_src[i1] : -1;
        uint4 u0 = make_uint4(0, 0, 0, 0);
        uint4 u1 = make_uint4(0, 0, 0, 0);
        if (r0 >= 0 && qv) u0 = *(const uint4*)&hs[(size_t)r0 * HSTRIDE + q * 8];
        if (r1 >= 0 && qv) u1 = *(const uint4*)&hs[(size_t)r1 * HSTRIDE + q * 8];
        acc_pair8(acc, u0, u1);
    }

#pragma unroll
    for (int m = 8; m <= 32; m <<= 1)
#pragma unroll
        for (int j = 0; j < 8; ++j) acc[j] += __shfl_xor(acc[j], m, 64);

    if (g == 0 && qv) {
        float o[8];
#pragma unroll
        for (int j = 0; j < 8; ++j) {
            float v = fmaf(acc[j], dc, b[q * 8 + j]);
            o[j] = RELU ? fmaxf(v, 0.f) : v;
        }
        if constexpr (std::is_same<OutT, float>::value) {
            float* dst = &out[(size_t)c * OUTSTRIDE + q * 8];
            *(float4*)dst = make_float4(o[0], o[1], o[2], o[3]);
            *(float4*)(dst + 4) = make_float4(o[4], o[5], o[6], o[7]);
        } else {
            __half2 pk[4];
#pragma unroll
            for (int k = 0; k < 4; ++k) pk[k] = __floats2half2_rn(o[2 * k], o[2 * k + 1]);
            *(uint4*)&out[(size_t)c * OUTSTRIDE + q * 8] = *(uint4*)pk;
        }
    }
}

// ---------------- launch ----------------

extern "C" void kernel_launch(void* const* d_in, const int* in_sizes, int n_in,
                              void* d_out, int out_size, void* d_ws, size_t ws_size,
                              hipStream_t stream) {
    const float* x = (const float*)d_in[0];
    const int* row = (const int*)d_in[1];
    const int* col = row + N_EDGES;
    const float* W1 = (const float*)d_in[2];
    const float* b1 = (const float*)d_in[3];
    const float* W2 = (const float*)d_in[4];
    const float* b2 = (const float*)d_in[5];
    float* out = (float*)d_out;

    const int N = N_NODES, E = N_EDGES;

    // 256B-aligned workspace carve-up: h1s/agg1h rows must be 128B-aligned so a
    // random 128B row spans exactly 2 cache lines.
    char* p = (char*)d_ws;
    auto alloc = [&](size_t bytes) {
        char* q = p;
        p += (bytes + 255) & ~(size_t)255;
        return q;
    };
    int* rowptr = (int*)alloc((size_t)(N + 1) * 4);
    int* csr_src = (int*)alloc((size_t)E * 4);
    int* gcursor = (int*)alloc((size_t)NBK * 4);
    unsigned* bke = (unsigned*)alloc((size_t)NBK * BCAP * 4);
    float* dinv = (float*)alloc((size_t)N * 4);
    __half* h1s = (__half*)alloc((size_t)N * HIDDEN * 2);     // stride 64 halves
    __half* agg1h = (__half*)alloc((size_t)N * HIDDEN * 2);   // fp16 agg, stride 64
    __half* h2s = (__half*)alloc((size_t)N * N_CLASSES * 2);  // packed stride 40 halves

    // CSR build: memset + 2 kernels
    hipMemsetAsync(gcursor, 0, (size_t)NBK * 4, stream);
    bucket_kernel<<<(E + CHUNK - 1) / CHUNK, 256, 0, stream>>>(row, col, gcursor, bke, E);
    place_kernel<<<NBK, 256, 0, stream>>>(gcursor, bke, rowptr, dinv, csr_src, N);

    // layer 1: fp32 X -> fp16 h1s (stride 64); gather -> fp16 agg1h
    gemm_mfma_kernel<float, N_FEAT, N_FEAT, HIDDEN, HIDDEN, HIDDEN>
        <<<(N + 255) / 256, 256, 0, stream>>>(x, W1, dinv, h1s, N);
    gather8_kernel<__half, 8, HIDDEN, HIDDEN, true>
        <<<(N + 3) / 4, 256, 0, stream>>>(rowptr, csr_src, dinv, h1s, b1, agg1h, N);

    // layer 2: fp16 agg1h -> packed h2s (stride 40); gather -> fp32 out
    gemm_mfma_kernel<_Float16, HIDDEN, HIDDEN, N_CLASSES, 48, N_CLASSES>
        <<<(N + 255) / 256, 256, 0, stream>>>((const _Float16*)agg1h, W2, dinv, h2s, N);
    gather8_kernel<float, 5, N_CLASSES, N_CLASSES, false>
        <<<(N + 3) / 4, 256, 0, stream>>>(rowptr, csr_src, dinv, h2s, b2, out, N);
}